// Round 1
// baseline (21.224 us; speedup 1.0000x reference)
//
#include <hip/hip_runtime.h>

// PseudoOneHotEncoding: out[b, l, :] = table[seq[b, l], :]
//   seq:   512*2048 int32 codes in [0, 27)
//   table: 27*21 fp32 (values 0 / 0.5 / 1.0)
//   out:   512*2048*21 fp32   (22,020,096 floats; divisible by 4)
//
// Memory-bound: ~88 MB written + ~4 MB read. Target ~15 us at 6.3 TB/s.

constexpr int NUM_CLASSES = 27;
constexpr int ALPHABET    = 21;
constexpr int TABLE_ELEMS = NUM_CLASSES * ALPHABET;  // 567 floats, 2.27 KB

__global__ __launch_bounds__(256) void pseudo_onehot_kernel(
    const int* __restrict__ seq,
    const float* __restrict__ table,
    float* __restrict__ out,
    int n_vec4,      // number of float4 outputs
    int total)       // total float outputs (for safety tail)
{
    __shared__ float t[TABLE_ELEMS];
    for (int i = threadIdx.x; i < TABLE_ELEMS; i += 256)
        t[i] = table[i];
    __syncthreads();

    const int tid     = blockIdx.x * 256 + threadIdx.x;
    const int nthread = gridDim.x * 256;

    // Main vectorized loop: one float4 (16 B) per lane per iteration.
    for (int g = tid; g < n_vec4; g += nthread) {
        const int base = g * 4;
        float v[4];
#pragma unroll
        for (int j = 0; j < 4; ++j) {
            const int idx  = base + j;
            const int e    = idx / ALPHABET;          // magic-mul, no div instr
            const int c    = idx - e * ALPHABET;
            const int code = seq[e];                  // L1-broadcast across lanes
            v[j] = t[code * ALPHABET + c];
        }
        float4 o = make_float4(v[0], v[1], v[2], v[3]);
        *reinterpret_cast<float4*>(out + base) = o;
    }

    // Safety tail (unused for 22,020,096, which is % 4 == 0).
    for (int idx = n_vec4 * 4 + tid; idx < total; idx += nthread) {
        const int e = idx / ALPHABET;
        const int c = idx - e * ALPHABET;
        out[idx] = t[seq[e] * ALPHABET + c];
    }
}

extern "C" void kernel_launch(void* const* d_in, const int* in_sizes, int n_in,
                              void* d_out, int out_size, void* d_ws, size_t ws_size,
                              hipStream_t stream) {
    const int*   seq   = (const int*)d_in[0];
    const float* table = (const float*)d_in[1];
    float*       out   = (float*)d_out;

    const int n_vec4 = out_size / 4;
    const int block  = 256;
    int grid = (n_vec4 + block - 1) / block;
    if (grid > 2048) grid = 2048;   // grid-stride; ~8 blocks/CU headroom

    pseudo_onehot_kernel<<<grid, block, 0, stream>>>(seq, table, out,
                                                     n_vec4, out_size);
}

// Round 2
// 19.814 us; speedup vs baseline: 1.0712x; 1.0712x over previous
//
#include <hip/hip_runtime.h>

// PseudoOneHotEncoding: out[e, :] = table[seq[e], :] for 512*2048 elements.
//   seq:   1,048,576 int32 codes in [0,27)
//   table: 27*21 fp32
//   out:   22,020,096 fp32  (= 1024 blocks * 21504 floats, exact)
//
// Write-BW bound. fillBuffer on this chip: ~6.6 TB/s -> floor ~14 us.
// Strategy: per-block element tile; codes staged (premultiplied by 21) in
// LDS so the hot loop has ZERO global loads — just LDS gathers + one
// float4 store per iteration.

constexpr int ALPHABET         = 21;
constexpr int TABLE_ELEMS      = 27 * 21;                      // 567
constexpr int BLOCK            = 256;
constexpr int ELEMS_PER_BLOCK  = 1024;                         // codes/block
constexpr int FLOATS_PER_BLOCK = ELEMS_PER_BLOCK * ALPHABET;   // 21504
constexpr int ITERS            = FLOATS_PER_BLOCK / 4 / BLOCK; // 21

__global__ __launch_bounds__(256) void pseudo_onehot_kernel(
    const int* __restrict__ seq,
    const float* __restrict__ table,
    float* __restrict__ out,
    int n_elems,
    long n_floats)
{
    __shared__ float t[TABLE_ELEMS];
    __shared__ int   codes21[ELEMS_PER_BLOCK + 4];  // code*21, +pad for le+1 read

    // Stage table (567 floats).
    for (int i = threadIdx.x; i < TABLE_ELEMS; i += BLOCK)
        t[i] = table[i];

    // Stage this block's 1024 codes, premultiplied by 21.
    const int eBase = blockIdx.x * ELEMS_PER_BLOCK;
    {
        const int i = threadIdx.x;                 // 256 threads * int4 = 1024
        const int e = eBase + i * 4;
        int4 c4;
        if (e + 3 < n_elems) {
            c4 = *reinterpret_cast<const int4*>(seq + e);
        } else {                                    // generic tail guard (unused here)
            c4.x = (e + 0 < n_elems) ? seq[e + 0] : 0;
            c4.y = (e + 1 < n_elems) ? seq[e + 1] : 0;
            c4.z = (e + 2 < n_elems) ? seq[e + 2] : 0;
            c4.w = (e + 3 < n_elems) ? seq[e + 3] : 0;
        }
        c4.x *= ALPHABET; c4.y *= ALPHABET; c4.z *= ALPHABET; c4.w *= ALPHABET;
        *reinterpret_cast<int4*>(&codes21[i * 4]) = c4;   // ds_write_b128
        if (i == 0) {                                     // pad slot for le+1
            codes21[ELEMS_PER_BLOCK]     = 0;
            codes21[ELEMS_PER_BLOCK + 1] = 0;
        }
    }
    __syncthreads();

    const long blockFloatBase = (long)blockIdx.x * FLOATS_PER_BLOCK;

#pragma unroll
    for (int j = 0; j < ITERS; ++j) {
        const int  f  = threadIdx.x + j * BLOCK;   // local float4 index, coalesced
        const int  lf = f * 4;                     // local float offset
        const long gf = blockFloatBase + lf;
        if (gf + 3 >= n_floats) break;             // exact division -> never taken

        const int le = lf / ALPHABET;              // magic-mul
        const int lc = lf - le * ALPHABET;         // 0..20
        const int A  = codes21[le] + lc;           // row of first element
        const int B  = codes21[le + 1] + lc - ALPHABET; // row of next element

        float4 o;
        o.x = t[(lc + 0 < ALPHABET) ? A + 0 : B + 0];
        o.y = t[(lc + 1 < ALPHABET) ? A + 1 : B + 1];
        o.z = t[(lc + 2 < ALPHABET) ? A + 2 : B + 2];
        o.w = t[(lc + 3 < ALPHABET) ? A + 3 : B + 3];

        *reinterpret_cast<float4*>(out + gf) = o;  // 16 B coalesced store
    }
}

extern "C" void kernel_launch(void* const* d_in, const int* in_sizes, int n_in,
                              void* d_out, int out_size, void* d_ws, size_t ws_size,
                              hipStream_t stream) {
    const int*   seq   = (const int*)d_in[0];
    const float* table = (const float*)d_in[1];
    float*       out   = (float*)d_out;

    const int n_elems = in_sizes[0];                        // 1,048,576
    const int grid    = (n_elems + ELEMS_PER_BLOCK - 1) / ELEMS_PER_BLOCK; // 1024

    pseudo_onehot_kernel<<<grid, BLOCK, 0, stream>>>(seq, table, out,
                                                     n_elems, (long)out_size);
}